// Round 1
// baseline (295.595 us; speedup 1.0000x reference)
//
#include <hip/hip_runtime.h>

#define N_DRUG 572
#define DIM 512
#define MAXDEG 32
#define FS 17            // scan LDS stride: 16 cols + 1 pad

// ---------------------------------------------------------------------------
// pack_both: repack Wa (512x512) and linW (1024x512) into K-major panels:
//   P[c>>6][k>>2][c&63][k&3]  (each float4 = 4 consecutive k for one col)
// GEMM waves then read W as one perfectly-coalesced 1KB dwordx4 per 4k.
// Reads are coalesced along c; writes are contiguous 16B/lane.
// ---------------------------------------------------------------------------
__global__ __launch_bounds__(256) void pack_both(
    const float* __restrict__ Wa, const float* __restrict__ linW,
    float* __restrict__ waP, float* __restrict__ linP)
{
    const int g = blockIdx.x * 256 + threadIdx.x;
    if (g < 65536) {                       // Wa: (512/4)*512 elems
        const int c = g & 511, k4 = g >> 9;            // k4 in [0,128)
        const float4 v = make_float4(Wa[(size_t)(k4 * 4 + 0) * 512 + c],
                                     Wa[(size_t)(k4 * 4 + 1) * 512 + c],
                                     Wa[(size_t)(k4 * 4 + 2) * 512 + c],
                                     Wa[(size_t)(k4 * 4 + 3) * 512 + c]);
        *(float4*)&waP[((size_t)(c >> 6) * 128 + k4) * 256 + (c & 63) * 4] = v;
    } else {                               // linW: (1024/4)*512 elems
        const int h = g - 65536;
        const int c = h & 511, k4 = h >> 9;            // k4 in [0,256)
        const float4 v = make_float4(linW[(size_t)(k4 * 4 + 0) * 512 + c],
                                     linW[(size_t)(k4 * 4 + 1) * 512 + c],
                                     linW[(size_t)(k4 * 4 + 2) * 512 + c],
                                     linW[(size_t)(k4 * 4 + 3) * 512 + c]);
        *(float4*)&linP[((size_t)(c >> 6) * 256 + k4) * 256 + (c & 63) * 4] = v;
    }
}

// ---------------------------------------------------------------------------
// gemm_q: q[572][512] = drugW[drug_name] @ Wa.
// grid (18,8) x 256 threads. Each wave owns 8 rows x 64 cols, no LDS, no
// barriers. A-row loads are wave-uniform (scalar pipe); W loads are one
// coalesced float4 per 4k from the packed panel. 576 waves ~ 2.25/CU.
// ---------------------------------------------------------------------------
__global__ __launch_bounds__(256) void gemm_q(
    const float* __restrict__ drugW, const float* __restrict__ waP,
    const int* __restrict__ dn, float* __restrict__ q)
{
    const int wv = threadIdx.x >> 6;
    const int lane = threadIdx.x & 63;
    const int r0 = (blockIdx.x * 4 + wv) * 8;          // 0..568
    const int c = blockIdx.y * 64 + lane;

    const float* ap[8];
    #pragma unroll
    for (int r = 0; r < 8; ++r) {
        const int rr = min(r0 + r, N_DRUG - 1);
        ap[r] = drugW + (size_t)dn[rr] * 512;
    }
    const float* wp = waP + (size_t)blockIdx.y * 128 * 256 + lane * 4;

    float acc[8] = {0.f, 0.f, 0.f, 0.f, 0.f, 0.f, 0.f, 0.f};
    #pragma unroll 4
    for (int k4 = 0; k4 < 128; ++k4) {
        const float4 w = *(const float4*)(wp + (size_t)k4 * 256);
        const int k = k4 * 4;
        #pragma unroll
        for (int r = 0; r < 8; ++r) {
            const float4 a = *(const float4*)(ap[r] + k);
            acc[r] = fmaf(a.x, w.x, acc[r]);
            acc[r] = fmaf(a.y, w.y, acc[r]);
            acc[r] = fmaf(a.z, w.z, acc[r]);
            acc[r] = fmaf(a.w, w.w, acc[r]);
        }
    }
    #pragma unroll
    for (int r = 0; r < 8; ++r)
        if (r0 + r < N_DRUG) q[(size_t)(r0 + r) * 512 + c] = acc[r];
}

// ---------------------------------------------------------------------------
// attn_kernel: one block per drug. scores -> softmax -> agg gather.
// Writes cat[d] = [agg | drug_e]. 572 blocks x 256 threads gives ~9 waves/CU
// of independent entW gathers -> HBM-BW-bound instead of latency-bound.
// ---------------------------------------------------------------------------
__global__ __launch_bounds__(256) void attn_kernel(
    const float* __restrict__ drugW, const float* __restrict__ relaW,
    const float* __restrict__ entW, const float* __restrict__ qbuf,
    const int* __restrict__ dn, const int* __restrict__ adj_tail,
    const int* __restrict__ adj_rel, float* __restrict__ cat)
{
    __shared__ float at[64];
    __shared__ int tails[64];
    __shared__ int rels[64];
    const int d = blockIdx.x;
    const int t = threadIdx.x;
    const int w = t >> 6, lane = t & 63;

    if (t < 64) {
        tails[t] = adj_tail[d * 64 + t];
        rels[t]  = adj_rel[d * 64 + t];
    }
    float qv[8];
    {
        const float4* qp = (const float4*)(qbuf + (size_t)d * 512 + lane * 8);
        const float4 x = qp[0], y = qp[1];
        qv[0] = x.x; qv[1] = x.y; qv[2] = x.z; qv[3] = x.w;
        qv[4] = y.x; qv[5] = y.y; qv[6] = y.z; qv[7] = y.w;
    }
    __syncthreads();

    // scores: wave w handles k = w*16 .. w*16+15
    #pragma unroll 4
    for (int kk = 0; kk < 16; ++kk) {
        const int k = w * 16 + kk;
        const float4* p = (const float4*)(relaW + (size_t)rels[k] * 512 + lane * 8);
        const float4 x = p[0], y = p[1];
        float s = 0.f;
        s = fmaf(qv[0], x.x, s); s = fmaf(qv[1], x.y, s);
        s = fmaf(qv[2], x.z, s); s = fmaf(qv[3], x.w, s);
        s = fmaf(qv[4], y.x, s); s = fmaf(qv[5], y.y, s);
        s = fmaf(qv[6], y.z, s); s = fmaf(qv[7], y.w, s);
        #pragma unroll
        for (int off = 32; off >= 1; off >>= 1) s += __shfl_xor(s, off, 64);
        if (lane == 0) at[k] = s * 0.0441941738241592f;   // 1/sqrt(512)
    }
    __syncthreads();

    // softmax over 64 scores (wave 0)
    if (w == 0) {
        const float s = at[lane];
        float m = s;
        #pragma unroll
        for (int off = 32; off >= 1; off >>= 1) m = fmaxf(m, __shfl_xor(m, off, 64));
        const float e = __expf(s - m);
        float sum = e;
        #pragma unroll
        for (int off = 32; off >= 1; off >>= 1) sum += __shfl_xor(sum, off, 64);
        at[lane] = e / sum;
    }
    __syncthreads();

    // agg: thread owns 2 cols; 64 independent float2 gathers from entW
    {
        const int c2 = t * 2;
        float a0 = 0.f, a1 = 0.f;
        #pragma unroll 8
        for (int k = 0; k < 64; ++k) {
            const float ak = at[k];
            const float2 e = *(const float2*)(entW + (size_t)tails[k] * 512 + c2);
            a0 = fmaf(ak, e.x, a0);
            a1 = fmaf(ak, e.y, a1);
        }
        float* o = cat + (size_t)d * 1024;
        *(float2*)&o[c2] = make_float2(a0, a1);
        const float2 de = *(const float2*)(drugW + (size_t)dn[d] * 512 + c2);
        *(float2*)&o[512 + c2] = de;
    }
}

// ---------------------------------------------------------------------------
// gemm_h: out[572][512] = ReLU(cat @ linW + b). Same wave-outer-product
// structure as gemm_q, K=1024.
// ---------------------------------------------------------------------------
__global__ __launch_bounds__(256) void gemm_h(
    const float* __restrict__ A, const float* __restrict__ linP,
    const float* __restrict__ bias, float* __restrict__ out)
{
    const int wv = threadIdx.x >> 6;
    const int lane = threadIdx.x & 63;
    const int r0 = (blockIdx.x * 4 + wv) * 8;
    const int c = blockIdx.y * 64 + lane;

    const float* ap[8];
    #pragma unroll
    for (int r = 0; r < 8; ++r)
        ap[r] = A + (size_t)min(r0 + r, N_DRUG - 1) * 1024;
    const float* wp = linP + (size_t)blockIdx.y * 256 * 256 + lane * 4;

    float acc[8] = {0.f, 0.f, 0.f, 0.f, 0.f, 0.f, 0.f, 0.f};
    #pragma unroll 4
    for (int k4 = 0; k4 < 256; ++k4) {
        const float4 w = *(const float4*)(wp + (size_t)k4 * 256);
        const int k = k4 * 4;
        #pragma unroll
        for (int r = 0; r < 8; ++r) {
            const float4 a = *(const float4*)(ap[r] + k);
            acc[r] = fmaf(a.x, w.x, acc[r]);
            acc[r] = fmaf(a.y, w.y, acc[r]);
            acc[r] = fmaf(a.z, w.z, acc[r]);
            acc[r] = fmaf(a.w, w.w, acc[r]);
        }
    }
    const float b = bias[c];
    #pragma unroll
    for (int r = 0; r < 8; ++r)
        if (r0 + r < N_DRUG)
            out[(size_t)(r0 + r) * 512 + c] = fmaxf(acc[r] + b, 0.f);
}

// ---------------------------------------------------------------------------
// Fused BN + sequential smoothing scan. 32 blocks x 16 cols, 512 threads.
// (unchanged from baseline)
// ---------------------------------------------------------------------------
__global__ __launch_bounds__(512) void scan_kernel(
    float* hout, const float* __restrict__ gamma, const float* __restrict__ beta,
    const int* __restrict__ nbr_idx, const int* __restrict__ nbr_deg,
    const int* __restrict__ epoch)
{
    __shared__ float fs[(N_DRUG + 1) * FS];      // row N_DRUG = zeros (dummy)
    __shared__ alignas(16) unsigned short offs[N_DRUG * MAXDEG];  // row*FS, dummy=N_DRUG*FS
    __shared__ float2 ivw[N_DRUG];               // (0.5/deg, 0.5) or (0,1)
    __shared__ int   mxs[N_DRUG];                // max lower-dep row, -1 if none
    __shared__ float part[2][32][16];
    __shared__ float bnp[2][16];
    __shared__ int   genext[2];
    __shared__ int   ge0s;

    const int t  = threadIdx.x;
    const int c  = t & 15;
    const int h  = (t >> 4) & 1;
    const int j  = t >> 5;         // node slot 0..15
    const int rr = t >> 4;         // staging row-group 0..31
    const int c0 = blockIdx.x * 16;

    // ---- phase 0a: padded, pre-scaled u16 neighbor table; mx; ivw ----
    for (int i = t; i < N_DRUG; i += 512) {
        const int d = nbr_deg[i];
        ivw[i] = (d > 0) ? make_float2(0.5f / (float)d, 0.5f) : make_float2(0.f, 1.f);
        const int4* np = (const int4*)&nbr_idx[i * MAXDEG];
        unsigned* op = (unsigned*)&offs[i * MAXDEG];
        int mx = -1;
        #pragma unroll
        for (int u = 0; u < 8; ++u) {
            int4 qq = np[u];
            const int b = u * 4;
            qq.x = (b + 0 < d) ? qq.x : N_DRUG;
            qq.y = (b + 1 < d) ? qq.y : N_DRUG;
            qq.z = (b + 2 < d) ? qq.z : N_DRUG;
            qq.w = (b + 3 < d) ? qq.w : N_DRUG;
            mx = max(mx, (qq.x < i) ? qq.x : -1);
            mx = max(mx, (qq.y < i) ? qq.y : -1);
            mx = max(mx, (qq.z < i) ? qq.z : -1);
            mx = max(mx, (qq.w < i) ? qq.w : -1);
            op[2 * u]     = (unsigned)(qq.x * FS) | ((unsigned)(qq.y * FS) << 16);
            op[2 * u + 1] = (unsigned)(qq.z * FS) | ((unsigned)(qq.w * FS) << 16);
        }
        mxs[i] = mx;
    }

    // ---- phase 0b: stage fs (already bias+ReLU'd); partial stats ----
    {
        float sl = 0.f, ql = 0.f;
        for (int r = rr; r < N_DRUG; r += 32) {
            const float v = hout[(size_t)r * DIM + c0 + c];
            fs[r * FS + c] = v;
            sl += v;
            ql = fmaf(v, v, ql);
        }
        part[0][rr][c] = sl;
        part[1][rr][c] = ql;
    }
    if (t < FS) fs[N_DRUG * FS + t] = 0.f;
    __syncthreads();

    // ---- phase 1: stats finalize (t<16) || first group boundary (wave 7) ----
    if (t < 16) {
        float s = 0.f, sq = 0.f;
        #pragma unroll
        for (int k = 0; k < 32; ++k) { s += part[0][k][t]; sq += part[1][k][t]; }
        const float mean = s * (1.f / N_DRUG);
        const float var = sq * (1.f / N_DRUG) - mean * mean;
        const float rstd = rsqrtf(var + 1e-5f);
        const float scl = gamma[c0 + t] * rstd;
        bnp[0][t] = scl;
        bnp[1][t] = beta[c0 + t] - mean * scl;
    }
    if ((t >> 6) == 7) {
        const int l = t & 63;
        const int jj = 1 + l;
        const bool flag = (l >= 15) || (jj >= N_DRUG) || (mxs[min(jj, N_DRUG - 1)] >= 0);
        const unsigned long long b = __ballot(flag) & 0xFFFFULL;
        if (l == 0) ge0s = 1 + (int)__builtin_ctzll(b);
    }
    __syncthreads();

    // ---- phase 2: BN apply ----
    {
        const float scl = bnp[0][c];
        const float shf = bnp[1][c];
        for (int r = rr; r < N_DRUG; r += 32)
            fs[r * FS + c] = fmaf(fs[r * FS + c], scl, shf);
    }
    __syncthreads();

    // ---- rounds ----
    if (epoch[0] > 1) {
        int gs = 0, ge = ge0s;
        uint4 ca, cb;
        {
            const uint4* p = (const uint4*)&offs[min(j, N_DRUG - 1) * MAXDEG + h * 16];
            ca = p[0]; cb = p[1];
        }
        int par = 0;
        while (gs < N_DRUG) {
            const bool pred = (gs + j) < ge;
            float s0 = 0.f, s1 = 0.f;
#define G2(W) { s0 += fs[(W & 0xffffu) + c]; s1 += fs[(W >> 16) + c]; }
            if (pred) { G2(ca.x) G2(ca.y) G2(ca.z) G2(ca.w)
                        G2(cb.x) G2(cb.y) G2(cb.z) G2(cb.w) }
#undef G2
            uint4 na, nb;
            {
                const uint4* p = (const uint4*)&offs[min(ge + j, N_DRUG - 1) * MAXDEG + h * 16];
                na = p[0]; nb = p[1];
            }
            float nv = 0.f;
            if (pred) {
                const float cur = fs[(gs + j) * FS + c];
                const float2 iw = ivw[gs + j];
                float sh = s0 + s1;
                sh += __shfl_xor(sh, 16, 64);    // combine the two halves
                nv = fmaf(sh, iw.x, cur * iw.y);
            }
            if ((t >> 6) == 7) {
                const int l = t & 63;
                const int jj = ge + 1 + l;
                const bool flag = (l >= 15) || (jj >= N_DRUG) ||
                                  (mxs[min(jj, N_DRUG - 1)] >= ge);
                const unsigned long long b = __ballot(flag) & 0xFFFFULL;
                if (l == 0) genext[par] = ge + 1 + (int)__builtin_ctzll(b);
            }
            __syncthreads();   // all reads done before any write (anti-deps)
            if (pred && h == 0) fs[(gs + j) * FS + c] = nv;
            __syncthreads();   // writes + genext visible
            gs = ge;
            ge = genext[par];
            par ^= 1;
            ca = na; cb = nb;
        }
    }
    __syncthreads();

    // ---- write back ----
    for (int r = rr; r < N_DRUG; r += 32)
        hout[(size_t)r * DIM + c0 + c] = fs[r * FS + c];
}

extern "C" void kernel_launch(void* const* d_in, const int* in_sizes, int n_in,
                              void* d_out, int out_size, void* d_ws, size_t ws_size,
                              hipStream_t stream)
{
    const float* drugW = (const float*)d_in[0];
    const float* relaW = (const float*)d_in[1];
    const float* entW  = (const float*)d_in[2];
    const float* Wa    = (const float*)d_in[3];
    const float* linW  = (const float*)d_in[4];
    const float* linb  = (const float*)d_in[5];
    const float* gamma = (const float*)d_in[6];
    const float* beta  = (const float*)d_in[7];
    const int* drug_name = (const int*)d_in[8];
    const int* adj_tail  = (const int*)d_in[9];
    const int* adj_rel   = (const int*)d_in[10];
    const int* nbr_idx   = (const int*)d_in[11];
    const int* nbr_deg   = (const int*)d_in[12];
    const int* epoch     = (const int*)d_in[13];

    float* out = (float*)d_out;    // h lives in d_out; scan updates in place

    // workspace layout (16B-aligned):
    //   qbuf: 572*512*4      = 1,171,456
    //   cat : 572*1024*4     = 2,342,912
    //   waP : 512*512*4      = 1,048,576
    //   linP: 1024*512*4     = 2,097,152   (total ~6.35 MB)
    float* qbuf = (float*)d_ws;
    float* cat  = (float*)((char*)d_ws + 1171456);
    float* waP  = (float*)((char*)d_ws + 3514368);
    float* linP = (float*)((char*)d_ws + 4562944);

    pack_both<<<768, 256, 0, stream>>>(Wa, linW, waP, linP);
    gemm_q<<<dim3(18, 8), 256, 0, stream>>>(drugW, waP, drug_name, qbuf);
    attn_kernel<<<N_DRUG, 256, 0, stream>>>(drugW, relaW, entW, qbuf,
                                            drug_name, adj_tail, adj_rel, cat);
    gemm_h<<<dim3(18, 8), 256, 0, stream>>>(cat, linP, linb, out);
    scan_kernel<<<32, 512, 0, stream>>>(out, gamma, beta, nbr_idx, nbr_deg, epoch);
}

// Round 2
// 238.870 us; speedup vs baseline: 1.2375x; 1.2375x over previous
//
#include <hip/hip_runtime.h>

#define N_DRUG 572
#define DIM 512
#define MAXDEG 32
#define FS 17            // scan LDS stride: 16 cols + 1 pad

// ---------------------------------------------------------------------------
// prep_kernel: one launch, two independent jobs split by block range.
//  blocks [0,512):  pack linW (1024x512) into K-major panels
//                   linP[c>>6][k4][c&63][4k] -> gemm_h reads 1KB dwordx4/4k.
//  blocks [512,928): relaP[200][512] = relaW @ Wa^T  (relaP[r][k] =
//                   sum_c relaW[r][c]*Wa[k][c]).  score = q . rela
//                   = drugE . relaP[rel], so the per-drug q GEMM vanishes.
//                   Lane-split-c shuffle GEMM: wave = 4r x 16k, lane owns an
//                   8-float c-slice, butterfly-reduce at the end.
// ---------------------------------------------------------------------------
__global__ __launch_bounds__(256) void prep_kernel(
    const float* __restrict__ Wa, const float* __restrict__ relaW,
    const float* __restrict__ linW, float* __restrict__ linP,
    float* __restrict__ relaP)
{
    const int b = blockIdx.x;
    const int t = threadIdx.x;
    if (b < 512) {                          // ---- pack linW ----
        const int g = b * 256 + t;          // [0,131072)
        const int c = g & 511, k4 = g >> 9; // k4 in [0,256)
        const float4 v = make_float4(linW[(size_t)(k4 * 4 + 0) * 512 + c],
                                     linW[(size_t)(k4 * 4 + 1) * 512 + c],
                                     linW[(size_t)(k4 * 4 + 2) * 512 + c],
                                     linW[(size_t)(k4 * 4 + 3) * 512 + c]);
        *(float4*)&linP[((size_t)(c >> 6) * 256 + k4) * 256 + (c & 63) * 4] = v;
        return;
    }
    // ---- relaP = relaW @ Wa^T ----
    const int bb = b - 512;                 // [0,416): 13 r-groups x 32 k-panels
    const int rb = bb >> 5, kb = bb & 31;
    const int wv = t >> 6, l = t & 63;
    const int r0 = rb * 16 + wv * 4;        // 4 rows per wave
    const int k0 = kb * 16;                 // 16 output cols per wave

    float a[4][8];
    #pragma unroll
    for (int rr = 0; rr < 4; ++rr) {
        const float4* ap = (const float4*)(relaW + (size_t)min(r0 + rr, 199) * 512 + l * 8);
        const float4 x = ap[0], y = ap[1];
        a[rr][0] = x.x; a[rr][1] = x.y; a[rr][2] = x.z; a[rr][3] = x.w;
        a[rr][4] = y.x; a[rr][5] = y.y; a[rr][6] = y.z; a[rr][7] = y.w;
    }
    float acc[64];
    #pragma unroll
    for (int i = 0; i < 64; ++i) acc[i] = 0.f;
    #pragma unroll
    for (int kk = 0; kk < 16; ++kk) {       // full unroll: acc index compile-time
        const float4* bp = (const float4*)(Wa + (size_t)(k0 + kk) * 512 + l * 8);
        const float4 x = bp[0], y = bp[1];
        const float bv[8] = {x.x, x.y, x.z, x.w, y.x, y.y, y.z, y.w};
        #pragma unroll
        for (int rr = 0; rr < 4; ++rr) {
            float s = acc[rr * 16 + kk];
            #pragma unroll
            for (int j = 0; j < 8; ++j) s = fmaf(a[rr][j], bv[j], s);
            acc[rr * 16 + kk] = s;
        }
    }
    #pragma unroll
    for (int off = 1; off <= 32; off <<= 1) {
        #pragma unroll
        for (int i = 0; i < 64; ++i) acc[i] += __shfl_xor(acc[i], off, 64);
    }
    // every lane now holds all 64 sums; lane l writes output l (static select,
    // no runtime array index -> no scratch)
    float outv = acc[0];
    #pragma unroll
    for (int i = 1; i < 64; ++i) outv = (l == i) ? acc[i] : outv;
    const int rr = l >> 4, kk = l & 15;
    if (r0 + rr < 200) relaP[(size_t)(r0 + rr) * 512 + k0 + kk] = outv;
}

// ---------------------------------------------------------------------------
// attn_kernel: one block per drug. scores (vs relaP) -> softmax -> agg gather.
// Writes cat[d] = [agg | drug_e]. 572 blocks x 256 threads ~ 9 waves/CU of
// independent entW gathers.
// ---------------------------------------------------------------------------
__global__ __launch_bounds__(256) void attn_kernel(
    const float* __restrict__ drugW, const float* __restrict__ relaP,
    const float* __restrict__ entW, const int* __restrict__ dn,
    const int* __restrict__ adj_tail, const int* __restrict__ adj_rel,
    float* __restrict__ cat)
{
    __shared__ float at[64];
    __shared__ int tails[64];
    __shared__ int rels[64];
    const int d = blockIdx.x;
    const int t = threadIdx.x;
    const int w = t >> 6, lane = t & 63;

    if (t < 64) {
        tails[t] = adj_tail[d * 64 + t];
        rels[t]  = adj_rel[d * 64 + t];
    }
    const int rd = dn[d];
    float qv[8];
    {
        const float4* qp = (const float4*)(drugW + (size_t)rd * 512 + lane * 8);
        const float4 x = qp[0], y = qp[1];
        qv[0] = x.x; qv[1] = x.y; qv[2] = x.z; qv[3] = x.w;
        qv[4] = y.x; qv[5] = y.y; qv[6] = y.z; qv[7] = y.w;
    }
    __syncthreads();

    // scores: wave w handles k = w*16 .. w*16+15; score = drugE . relaP[rel]
    #pragma unroll 4
    for (int kk = 0; kk < 16; ++kk) {
        const int k = w * 16 + kk;
        const float4* p = (const float4*)(relaP + (size_t)rels[k] * 512 + lane * 8);
        const float4 x = p[0], y = p[1];
        float s = 0.f;
        s = fmaf(qv[0], x.x, s); s = fmaf(qv[1], x.y, s);
        s = fmaf(qv[2], x.z, s); s = fmaf(qv[3], x.w, s);
        s = fmaf(qv[4], y.x, s); s = fmaf(qv[5], y.y, s);
        s = fmaf(qv[6], y.z, s); s = fmaf(qv[7], y.w, s);
        #pragma unroll
        for (int off = 32; off >= 1; off >>= 1) s += __shfl_xor(s, off, 64);
        if (lane == 0) at[k] = s * 0.0441941738241592f;   // 1/sqrt(512)
    }
    __syncthreads();

    // softmax over 64 scores (wave 0)
    if (w == 0) {
        const float s = at[lane];
        float m = s;
        #pragma unroll
        for (int off = 32; off >= 1; off >>= 1) m = fmaxf(m, __shfl_xor(m, off, 64));
        const float e = __expf(s - m);
        float sum = e;
        #pragma unroll
        for (int off = 32; off >= 1; off >>= 1) sum += __shfl_xor(sum, off, 64);
        at[lane] = e / sum;
    }
    __syncthreads();

    // agg: thread owns 2 cols; 64 independent float2 gathers from entW
    {
        const int c2 = t * 2;
        float a0 = 0.f, a1 = 0.f;
        #pragma unroll 8
        for (int k = 0; k < 64; ++k) {
            const float ak = at[k];
            const float2 e = *(const float2*)(entW + (size_t)tails[k] * 512 + c2);
            a0 = fmaf(ak, e.x, a0);
            a1 = fmaf(ak, e.y, a1);
        }
        float* o = cat + (size_t)d * 1024;
        *(float2*)&o[c2] = make_float2(a0, a1);
        const float2 de = *(const float2*)(drugW + (size_t)rd * 512 + c2);
        *(float2*)&o[512 + c2] = de;
    }
}

// ---------------------------------------------------------------------------
// gemm_h: out[572][512] = ReLU(cat @ linW + b).
// grid (72,8) x 256: block = 8 rows x 64 cols; wave owns a K-quarter (256 k)
// so the W panel is streamed exactly once per block; LDS-reduce 4 partials.
// 576 blocks = 2.25 blocks/CU = 9 waves/CU.
// ---------------------------------------------------------------------------
__global__ __launch_bounds__(256) void gemm_h(
    const float* __restrict__ A, const float* __restrict__ linP,
    const float* __restrict__ bias, float* __restrict__ out)
{
    __shared__ float red[4][8][64];
    const int t = threadIdx.x;
    const int wv = t >> 6, lane = t & 63;
    const int r0 = blockIdx.x * 8;

    const float* wp = linP + ((size_t)blockIdx.y * 256 + wv * 64) * 256 + lane * 4;
    const float* ap[8];
    #pragma unroll
    for (int r = 0; r < 8; ++r)
        ap[r] = A + (size_t)min(r0 + r, N_DRUG - 1) * 1024 + wv * 256;

    float acc[8] = {0.f, 0.f, 0.f, 0.f, 0.f, 0.f, 0.f, 0.f};
    #pragma unroll 4
    for (int k4 = 0; k4 < 64; ++k4) {
        const float4 w = *(const float4*)(wp + (size_t)k4 * 256);
        #pragma unroll
        for (int r = 0; r < 8; ++r) {
            const float4 a = *(const float4*)(ap[r] + k4 * 4);
            acc[r] = fmaf(a.x, w.x, acc[r]);
            acc[r] = fmaf(a.y, w.y, acc[r]);
            acc[r] = fmaf(a.z, w.z, acc[r]);
            acc[r] = fmaf(a.w, w.w, acc[r]);
        }
    }
    #pragma unroll
    for (int r = 0; r < 8; ++r) red[wv][r][lane] = acc[r];
    __syncthreads();

    #pragma unroll
    for (int u = 0; u < 2; ++u) {
        const int o = u * 256 + t;
        const int r = o >> 6, cc = o & 63;
        if (r0 + r < N_DRUG) {
            const float v = red[0][r][cc] + red[1][r][cc] + red[2][r][cc] + red[3][r][cc]
                          + bias[blockIdx.y * 64 + cc];
            out[(size_t)(r0 + r) * 512 + blockIdx.y * 64 + cc] = fmaxf(v, 0.f);
        }
    }
}

// ---------------------------------------------------------------------------
// Fused BN + sequential smoothing scan. 32 blocks x 16 cols, 512 threads.
// (unchanged from baseline)
// ---------------------------------------------------------------------------
__global__ __launch_bounds__(512) void scan_kernel(
    float* hout, const float* __restrict__ gamma, const float* __restrict__ beta,
    const int* __restrict__ nbr_idx, const int* __restrict__ nbr_deg,
    const int* __restrict__ epoch)
{
    __shared__ float fs[(N_DRUG + 1) * FS];      // row N_DRUG = zeros (dummy)
    __shared__ alignas(16) unsigned short offs[N_DRUG * MAXDEG];  // row*FS, dummy=N_DRUG*FS
    __shared__ float2 ivw[N_DRUG];               // (0.5/deg, 0.5) or (0,1)
    __shared__ int   mxs[N_DRUG];                // max lower-dep row, -1 if none
    __shared__ float part[2][32][16];
    __shared__ float bnp[2][16];
    __shared__ int   genext[2];
    __shared__ int   ge0s;

    const int t  = threadIdx.x;
    const int c  = t & 15;
    const int h  = (t >> 4) & 1;
    const int j  = t >> 5;         // node slot 0..15
    const int rr = t >> 4;         // staging row-group 0..31
    const int c0 = blockIdx.x * 16;

    // ---- phase 0a: padded, pre-scaled u16 neighbor table; mx; ivw ----
    for (int i = t; i < N_DRUG; i += 512) {
        const int d = nbr_deg[i];
        ivw[i] = (d > 0) ? make_float2(0.5f / (float)d, 0.5f) : make_float2(0.f, 1.f);
        const int4* np = (const int4*)&nbr_idx[i * MAXDEG];
        unsigned* op = (unsigned*)&offs[i * MAXDEG];
        int mx = -1;
        #pragma unroll
        for (int u = 0; u < 8; ++u) {
            int4 qq = np[u];
            const int b = u * 4;
            qq.x = (b + 0 < d) ? qq.x : N_DRUG;
            qq.y = (b + 1 < d) ? qq.y : N_DRUG;
            qq.z = (b + 2 < d) ? qq.z : N_DRUG;
            qq.w = (b + 3 < d) ? qq.w : N_DRUG;
            mx = max(mx, (qq.x < i) ? qq.x : -1);
            mx = max(mx, (qq.y < i) ? qq.y : -1);
            mx = max(mx, (qq.z < i) ? qq.z : -1);
            mx = max(mx, (qq.w < i) ? qq.w : -1);
            op[2 * u]     = (unsigned)(qq.x * FS) | ((unsigned)(qq.y * FS) << 16);
            op[2 * u + 1] = (unsigned)(qq.z * FS) | ((unsigned)(qq.w * FS) << 16);
        }
        mxs[i] = mx;
    }

    // ---- phase 0b: stage fs (already bias+ReLU'd); partial stats ----
    {
        float sl = 0.f, ql = 0.f;
        for (int r = rr; r < N_DRUG; r += 32) {
            const float v = hout[(size_t)r * DIM + c0 + c];
            fs[r * FS + c] = v;
            sl += v;
            ql = fmaf(v, v, ql);
        }
        part[0][rr][c] = sl;
        part[1][rr][c] = ql;
    }
    if (t < FS) fs[N_DRUG * FS + t] = 0.f;
    __syncthreads();

    // ---- phase 1: stats finalize (t<16) || first group boundary (wave 7) ----
    if (t < 16) {
        float s = 0.f, sq = 0.f;
        #pragma unroll
        for (int k = 0; k < 32; ++k) { s += part[0][k][t]; sq += part[1][k][t]; }
        const float mean = s * (1.f / N_DRUG);
        const float var = sq * (1.f / N_DRUG) - mean * mean;
        const float rstd = rsqrtf(var + 1e-5f);
        const float scl = gamma[c0 + t] * rstd;
        bnp[0][t] = scl;
        bnp[1][t] = beta[c0 + t] - mean * scl;
    }
    if ((t >> 6) == 7) {
        const int l = t & 63;
        const int jj = 1 + l;
        const bool flag = (l >= 15) || (jj >= N_DRUG) || (mxs[min(jj, N_DRUG - 1)] >= 0);
        const unsigned long long b = __ballot(flag) & 0xFFFFULL;
        if (l == 0) ge0s = 1 + (int)__builtin_ctzll(b);
    }
    __syncthreads();

    // ---- phase 2: BN apply ----
    {
        const float scl = bnp[0][c];
        const float shf = bnp[1][c];
        for (int r = rr; r < N_DRUG; r += 32)
            fs[r * FS + c] = fmaf(fs[r * FS + c], scl, shf);
    }
    __syncthreads();

    // ---- rounds ----
    if (epoch[0] > 1) {
        int gs = 0, ge = ge0s;
        uint4 ca, cb;
        {
            const uint4* p = (const uint4*)&offs[min(j, N_DRUG - 1) * MAXDEG + h * 16];
            ca = p[0]; cb = p[1];
        }
        int par = 0;
        while (gs < N_DRUG) {
            const bool pred = (gs + j) < ge;
            float s0 = 0.f, s1 = 0.f;
#define G2(W) { s0 += fs[(W & 0xffffu) + c]; s1 += fs[(W >> 16) + c]; }
            if (pred) { G2(ca.x) G2(ca.y) G2(ca.z) G2(ca.w)
                        G2(cb.x) G2(cb.y) G2(cb.z) G2(cb.w) }
#undef G2
            uint4 na, nb;
            {
                const uint4* p = (const uint4*)&offs[min(ge + j, N_DRUG - 1) * MAXDEG + h * 16];
                na = p[0]; nb = p[1];
            }
            float nv = 0.f;
            if (pred) {
                const float cur = fs[(gs + j) * FS + c];
                const float2 iw = ivw[gs + j];
                float sh = s0 + s1;
                sh += __shfl_xor(sh, 16, 64);    // combine the two halves
                nv = fmaf(sh, iw.x, cur * iw.y);
            }
            if ((t >> 6) == 7) {
                const int l = t & 63;
                const int jj = ge + 1 + l;
                const bool flag = (l >= 15) || (jj >= N_DRUG) ||
                                  (mxs[min(jj, N_DRUG - 1)] >= ge);
                const unsigned long long b = __ballot(flag) & 0xFFFFULL;
                if (l == 0) genext[par] = ge + 1 + (int)__builtin_ctzll(b);
            }
            __syncthreads();   // all reads done before any write (anti-deps)
            if (pred && h == 0) fs[(gs + j) * FS + c] = nv;
            __syncthreads();   // writes + genext visible
            gs = ge;
            ge = genext[par];
            par ^= 1;
            ca = na; cb = nb;
        }
    }
    __syncthreads();

    // ---- write back ----
    for (int r = rr; r < N_DRUG; r += 32)
        hout[(size_t)r * DIM + c0 + c] = fs[r * FS + c];
}

extern "C" void kernel_launch(void* const* d_in, const int* in_sizes, int n_in,
                              void* d_out, int out_size, void* d_ws, size_t ws_size,
                              hipStream_t stream)
{
    const float* drugW = (const float*)d_in[0];
    const float* relaW = (const float*)d_in[1];
    const float* entW  = (const float*)d_in[2];
    const float* Wa    = (const float*)d_in[3];
    const float* linW  = (const float*)d_in[4];
    const float* linb  = (const float*)d_in[5];
    const float* gamma = (const float*)d_in[6];
    const float* beta  = (const float*)d_in[7];
    const int* drug_name = (const int*)d_in[8];
    const int* adj_tail  = (const int*)d_in[9];
    const int* adj_rel   = (const int*)d_in[10];
    const int* nbr_idx   = (const int*)d_in[11];
    const int* nbr_deg   = (const int*)d_in[12];
    const int* epoch     = (const int*)d_in[13];

    float* out = (float*)d_out;    // h lives in d_out; scan updates in place

    // workspace layout (16B-aligned):
    //   linP : 1024*512*4 = 2,097,152   @ 0
    //   relaP:  200*512*4 =   409,600   @ 2,097,152
    //   cat  : 572*1024*4 = 2,342,912   @ 2,506,752   (total ~4.85 MB)
    float* linP  = (float*)d_ws;
    float* relaP = (float*)((char*)d_ws + 2097152);
    float* cat   = (float*)((char*)d_ws + 2506752);

    prep_kernel<<<928, 256, 0, stream>>>(Wa, relaW, linW, linP, relaP);
    attn_kernel<<<N_DRUG, 256, 0, stream>>>(drugW, relaP, entW, drug_name,
                                            adj_tail, adj_rel, cat);
    gemm_h<<<dim3(72, 8), 256, 0, stream>>>(cat, linP, linb, out);
    scan_kernel<<<32, 512, 0, stream>>>(out, gamma, beta, nbr_idx, nbr_deg, epoch);
}

// Round 4
// 227.120 us; speedup vs baseline: 1.3015x; 1.0517x over previous
//
#include <hip/hip_runtime.h>

#define N_DRUG 572
#define DIM 512
#define MAXDEG 32
#define FS 17            // scan LDS stride: 16 cols + 1 pad

// ---------------------------------------------------------------------------
// prep_kernel: one launch, two independent jobs split by block range.
//  blocks [0,512):  pack linW (1024x512) into K-major panels
//                   linP[c>>6][k4][c&63][4k] -> gemm_h reads 1KB dwordx4/4k.
//  blocks [512,928): relaP[200][512] = relaW @ Wa^T.  score = drugE . relaP[rel]
// ---------------------------------------------------------------------------
__global__ __launch_bounds__(256) void prep_kernel(
    const float* __restrict__ Wa, const float* __restrict__ relaW,
    const float* __restrict__ linW, float* __restrict__ linP,
    float* __restrict__ relaP)
{
    const int b = blockIdx.x;
    const int t = threadIdx.x;
    if (b < 512) {                          // ---- pack linW ----
        const int g = b * 256 + t;          // [0,131072)
        const int c = g & 511, k4 = g >> 9; // k4 in [0,256)
        const float4 v = make_float4(linW[(size_t)(k4 * 4 + 0) * 512 + c],
                                     linW[(size_t)(k4 * 4 + 1) * 512 + c],
                                     linW[(size_t)(k4 * 4 + 2) * 512 + c],
                                     linW[(size_t)(k4 * 4 + 3) * 512 + c]);
        *(float4*)&linP[((size_t)(c >> 6) * 256 + k4) * 256 + (c & 63) * 4] = v;
        return;
    }
    // ---- relaP = relaW @ Wa^T ----
    const int bb = b - 512;                 // [0,416): 13 r-groups x 32 k-panels
    const int rb = bb >> 5, kb = bb & 31;
    const int wv = t >> 6, l = t & 63;
    const int r0 = rb * 16 + wv * 4;        // 4 rows per wave
    const int k0 = kb * 16;                 // 16 output cols per wave

    float a[4][8];
    #pragma unroll
    for (int rr = 0; rr < 4; ++rr) {
        const float4* ap = (const float4*)(relaW + (size_t)min(r0 + rr, 199) * 512 + l * 8);
        const float4 x = ap[0], y = ap[1];
        a[rr][0] = x.x; a[rr][1] = x.y; a[rr][2] = x.z; a[rr][3] = x.w;
        a[rr][4] = y.x; a[rr][5] = y.y; a[rr][6] = y.z; a[rr][7] = y.w;
    }
    float acc[64];
    #pragma unroll
    for (int i = 0; i < 64; ++i) acc[i] = 0.f;
    #pragma unroll
    for (int kk = 0; kk < 16; ++kk) {       // full unroll: acc index compile-time
        const float4* bp = (const float4*)(Wa + (size_t)(k0 + kk) * 512 + l * 8);
        const float4 x = bp[0], y = bp[1];
        const float bv[8] = {x.x, x.y, x.z, x.w, y.x, y.y, y.z, y.w};
        #pragma unroll
        for (int rr = 0; rr < 4; ++rr) {
            float s = acc[rr * 16 + kk];
            #pragma unroll
            for (int j = 0; j < 8; ++j) s = fmaf(a[rr][j], bv[j], s);
            acc[rr * 16 + kk] = s;
        }
    }
    #pragma unroll
    for (int off = 1; off <= 32; off <<= 1) {
        #pragma unroll
        for (int i = 0; i < 64; ++i) acc[i] += __shfl_xor(acc[i], off, 64);
    }
    float outv = acc[0];
    #pragma unroll
    for (int i = 1; i < 64; ++i) outv = (l == i) ? acc[i] : outv;
    const int rr = l >> 4, kk = l & 15;
    if (r0 + rr < 200) relaP[(size_t)(r0 + rr) * 512 + k0 + kk] = outv;
}

// ---------------------------------------------------------------------------
// attn_kernel: one block per drug. scores (vs relaP) -> softmax -> agg gather.
// Writes cat[d] = [agg | drug_e]. (unchanged from round 2)
// ---------------------------------------------------------------------------
__global__ __launch_bounds__(256) void attn_kernel(
    const float* __restrict__ drugW, const float* __restrict__ relaP,
    const float* __restrict__ entW, const int* __restrict__ dn,
    const int* __restrict__ adj_tail, const int* __restrict__ adj_rel,
    float* __restrict__ cat)
{
    __shared__ float at[64];
    __shared__ int tails[64];
    __shared__ int rels[64];
    const int d = blockIdx.x;
    const int t = threadIdx.x;
    const int w = t >> 6, lane = t & 63;

    if (t < 64) {
        tails[t] = adj_tail[d * 64 + t];
        rels[t]  = adj_rel[d * 64 + t];
    }
    const int rd = dn[d];
    float qv[8];
    {
        const float4* qp = (const float4*)(drugW + (size_t)rd * 512 + lane * 8);
        const float4 x = qp[0], y = qp[1];
        qv[0] = x.x; qv[1] = x.y; qv[2] = x.z; qv[3] = x.w;
        qv[4] = y.x; qv[5] = y.y; qv[6] = y.z; qv[7] = y.w;
    }
    __syncthreads();

    #pragma unroll 4
    for (int kk = 0; kk < 16; ++kk) {
        const int k = w * 16 + kk;
        const float4* p = (const float4*)(relaP + (size_t)rels[k] * 512 + lane * 8);
        const float4 x = p[0], y = p[1];
        float s = 0.f;
        s = fmaf(qv[0], x.x, s); s = fmaf(qv[1], x.y, s);
        s = fmaf(qv[2], x.z, s); s = fmaf(qv[3], x.w, s);
        s = fmaf(qv[4], y.x, s); s = fmaf(qv[5], y.y, s);
        s = fmaf(qv[6], y.z, s); s = fmaf(qv[7], y.w, s);
        #pragma unroll
        for (int off = 32; off >= 1; off >>= 1) s += __shfl_xor(s, off, 64);
        if (lane == 0) at[k] = s * 0.0441941738241592f;   // 1/sqrt(512)
    }
    __syncthreads();

    if (w == 0) {
        const float s = at[lane];
        float m = s;
        #pragma unroll
        for (int off = 32; off >= 1; off >>= 1) m = fmaxf(m, __shfl_xor(m, off, 64));
        const float e = __expf(s - m);
        float sum = e;
        #pragma unroll
        for (int off = 32; off >= 1; off >>= 1) sum += __shfl_xor(sum, off, 64);
        at[lane] = e / sum;
    }
    __syncthreads();

    {
        const int c2 = t * 2;
        float a0 = 0.f, a1 = 0.f;
        #pragma unroll 8
        for (int k = 0; k < 64; ++k) {
            const float ak = at[k];
            const float2 e = *(const float2*)(entW + (size_t)tails[k] * 512 + c2);
            a0 = fmaf(ak, e.x, a0);
            a1 = fmaf(ak, e.y, a1);
        }
        float* o = cat + (size_t)d * 1024;
        *(float2*)&o[c2] = make_float2(a0, a1);
        const float2 de = *(const float2*)(drugW + (size_t)rd * 512 + c2);
        *(float2*)&o[512 + c2] = de;
    }
}

// ---------------------------------------------------------------------------
// gemm_h v3: out[572][512] = ReLU(cat @ linW + b).
// grid (72,4) x 512 threads: block = 8 rows x 128 cols; 8 waves, each owns a
// K-eighth (128 k = 32 k4-iters). Thread owns a COL-PAIR -> per k4-iter:
// 8 A-broadcast dwordx4 + 2 W dwordx4 = 10 vmem per 64 FMA-instr (128 cy),
// 2x better vmem:VALU than v2. unroll-2 keeps ~20 loads in flight.
// LDS-reduce the 8 K-partials; fused bias+ReLU.
// ---------------------------------------------------------------------------
__global__ __launch_bounds__(512) void gemm_h(
    const float* __restrict__ A, const float* __restrict__ linP,
    const float* __restrict__ bias, float* __restrict__ out)
{
    __shared__ float red[8][8][128];      // 32 KB
    const int t = threadIdx.x;
    const int wv = t >> 6, lane = t & 63;
    const int r0 = blockIdx.x * 8;
    const int half = lane >> 5;           // which 64-col linP panel of the pair
    const int cw = (lane * 2) & 63;       // col within panel (even)

    // W pointer: panel p = by*2+half, k4 window [wv*32, wv*32+32)
    const float* wp = linP + ((size_t)(blockIdx.y * 2 + half) * 256 + wv * 32) * 256
                    + cw * 4;
    const float* ap[8];
    #pragma unroll
    for (int r = 0; r < 8; ++r)
        ap[r] = A + (size_t)min(r0 + r, N_DRUG - 1) * 1024 + wv * 128;

    float acc0[8] = {0.f, 0.f, 0.f, 0.f, 0.f, 0.f, 0.f, 0.f};
    float acc1[8] = {0.f, 0.f, 0.f, 0.f, 0.f, 0.f, 0.f, 0.f};
    #pragma unroll 2
    for (int k4 = 0; k4 < 32; ++k4) {
        const float4 w0 = *(const float4*)(wp + (size_t)k4 * 256);
        const float4 w1 = *(const float4*)(wp + (size_t)k4 * 256 + 4);
        #pragma unroll
        for (int r = 0; r < 8; ++r) {
            const float4 a = *(const float4*)(ap[r] + k4 * 4);   // wave-uniform bcast
            acc0[r] = fmaf(a.x, w0.x, acc0[r]);
            acc0[r] = fmaf(a.y, w0.y, acc0[r]);
            acc0[r] = fmaf(a.z, w0.z, acc0[r]);
            acc0[r] = fmaf(a.w, w0.w, acc0[r]);
            acc1[r] = fmaf(a.x, w1.x, acc1[r]);
            acc1[r] = fmaf(a.y, w1.y, acc1[r]);
            acc1[r] = fmaf(a.z, w1.z, acc1[r]);
            acc1[r] = fmaf(a.w, w1.w, acc1[r]);
        }
    }
    #pragma unroll
    for (int r = 0; r < 8; ++r)
        *(float2*)&red[wv][r][lane * 2] = make_float2(acc0[r], acc1[r]);
    __syncthreads();

    // reduce 8 K-partials; 512 threads x 2 outputs cover 8 rows x 128 cols
    #pragma unroll
    for (int u = 0; u < 2; ++u) {
        const int o = u * 512 + t;
        const int r = o >> 7, cc = o & 127;
        if (r0 + r < N_DRUG) {
            float v = red[0][r][cc];
            #pragma unroll
            for (int w = 1; w < 8; ++w) v += red[w][r][cc];
            v += bias[blockIdx.y * 128 + cc];
            out[(size_t)(r0 + r) * 512 + blockIdx.y * 128 + cc] = fmaxf(v, 0.f);
        }
    }
}

// ---------------------------------------------------------------------------
// Fused BN + sequential smoothing scan. 32 blocks x 16 cols, 512 threads.
// (unchanged from baseline)
// ---------------------------------------------------------------------------
__global__ __launch_bounds__(512) void scan_kernel(
    float* hout, const float* __restrict__ gamma, const float* __restrict__ beta,
    const int* __restrict__ nbr_idx, const int* __restrict__ nbr_deg,
    const int* __restrict__ epoch)
{
    __shared__ float fs[(N_DRUG + 1) * FS];      // row N_DRUG = zeros (dummy)
    __shared__ alignas(16) unsigned short offs[N_DRUG * MAXDEG];  // row*FS, dummy=N_DRUG*FS
    __shared__ float2 ivw[N_DRUG];               // (0.5/deg, 0.5) or (0,1)
    __shared__ int   mxs[N_DRUG];                // max lower-dep row, -1 if none
    __shared__ float part[2][32][16];
    __shared__ float bnp[2][16];
    __shared__ int   genext[2];
    __shared__ int   ge0s;

    const int t  = threadIdx.x;
    const int c  = t & 15;
    const int h  = (t >> 4) & 1;
    const int j  = t >> 5;         // node slot 0..15
    const int rr = t >> 4;         // staging row-group 0..31
    const int c0 = blockIdx.x * 16;

    // ---- phase 0a: padded, pre-scaled u16 neighbor table; mx; ivw ----
    for (int i = t; i < N_DRUG; i += 512) {
        const int d = nbr_deg[i];
        ivw[i] = (d > 0) ? make_float2(0.5f / (float)d, 0.5f) : make_float2(0.f, 1.f);
        const int4* np = (const int4*)&nbr_idx[i * MAXDEG];
        unsigned* op = (unsigned*)&offs[i * MAXDEG];
        int mx = -1;
        #pragma unroll
        for (int u = 0; u < 8; ++u) {
            int4 qq = np[u];
            const int b = u * 4;
            qq.x = (b + 0 < d) ? qq.x : N_DRUG;
            qq.y = (b + 1 < d) ? qq.y : N_DRUG;
            qq.z = (b + 2 < d) ? qq.z : N_DRUG;
            qq.w = (b + 3 < d) ? qq.w : N_DRUG;
            mx = max(mx, (qq.x < i) ? qq.x : -1);
            mx = max(mx, (qq.y < i) ? qq.y : -1);
            mx = max(mx, (qq.z < i) ? qq.z : -1);
            mx = max(mx, (qq.w < i) ? qq.w : -1);
            op[2 * u]     = (unsigned)(qq.x * FS) | ((unsigned)(qq.y * FS) << 16);
            op[2 * u + 1] = (unsigned)(qq.z * FS) | ((unsigned)(qq.w * FS) << 16);
        }
        mxs[i] = mx;
    }

    // ---- phase 0b: stage fs (already bias+ReLU'd); partial stats ----
    {
        float sl = 0.f, ql = 0.f;
        for (int r = rr; r < N_DRUG; r += 32) {
            const float v = hout[(size_t)r * DIM + c0 + c];
            fs[r * FS + c] = v;
            sl += v;
            ql = fmaf(v, v, ql);
        }
        part[0][rr][c] = sl;
        part[1][rr][c] = ql;
    }
    if (t < FS) fs[N_DRUG * FS + t] = 0.f;
    __syncthreads();

    // ---- phase 1: stats finalize (t<16) || first group boundary (wave 7) ----
    if (t < 16) {
        float s = 0.f, sq = 0.f;
        #pragma unroll
        for (int k = 0; k < 32; ++k) { s += part[0][k][t]; sq += part[1][k][t]; }
        const float mean = s * (1.f / N_DRUG);
        const float var = sq * (1.f / N_DRUG) - mean * mean;
        const float rstd = rsqrtf(var + 1e-5f);
        const float scl = gamma[c0 + t] * rstd;
        bnp[0][t] = scl;
        bnp[1][t] = beta[c0 + t] - mean * scl;
    }
    if ((t >> 6) == 7) {
        const int l = t & 63;
        const int jj = 1 + l;
        const bool flag = (l >= 15) || (jj >= N_DRUG) || (mxs[min(jj, N_DRUG - 1)] >= 0);
        const unsigned long long b = __ballot(flag) & 0xFFFFULL;
        if (l == 0) ge0s = 1 + (int)__builtin_ctzll(b);
    }
    __syncthreads();

    // ---- phase 2: BN apply ----
    {
        const float scl = bnp[0][c];
        const float shf = bnp[1][c];
        for (int r = rr; r < N_DRUG; r += 32)
            fs[r * FS + c] = fmaf(fs[r * FS + c], scl, shf);
    }
    __syncthreads();

    // ---- rounds ----
    if (epoch[0] > 1) {
        int gs = 0, ge = ge0s;
        uint4 ca, cb;
        {
            const uint4* p = (const uint4*)&offs[min(j, N_DRUG - 1) * MAXDEG + h * 16];
            ca = p[0]; cb = p[1];
        }
        int par = 0;
        while (gs < N_DRUG) {
            const bool pred = (gs + j) < ge;
            float s0 = 0.f, s1 = 0.f;
#define G2(W) { s0 += fs[(W & 0xffffu) + c]; s1 += fs[(W >> 16) + c]; }
            if (pred) { G2(ca.x) G2(ca.y) G2(ca.z) G2(ca.w)
                        G2(cb.x) G2(cb.y) G2(cb.z) G2(cb.w) }
#undef G2
            uint4 na, nb;
            {
                const uint4* p = (const uint4*)&offs[min(ge + j, N_DRUG - 1) * MAXDEG + h * 16];
                na = p[0]; nb = p[1];
            }
            float nv = 0.f;
            if (pred) {
                const float cur = fs[(gs + j) * FS + c];
                const float2 iw = ivw[gs + j];
                float sh = s0 + s1;
                sh += __shfl_xor(sh, 16, 64);    // combine the two halves
                nv = fmaf(sh, iw.x, cur * iw.y);
            }
            if ((t >> 6) == 7) {
                const int l = t & 63;
                const int jj = ge + 1 + l;
                const bool flag = (l >= 15) || (jj >= N_DRUG) ||
                                  (mxs[min(jj, N_DRUG - 1)] >= ge);
                const unsigned long long b = __ballot(flag) & 0xFFFFULL;
                if (l == 0) genext[par] = ge + 1 + (int)__builtin_ctzll(b);
            }
            __syncthreads();   // all reads done before any write (anti-deps)
            if (pred && h == 0) fs[(gs + j) * FS + c] = nv;
            __syncthreads();   // writes + genext visible
            gs = ge;
            ge = genext[par];
            par ^= 1;
            ca = na; cb = nb;
        }
    }
    __syncthreads();

    // ---- write back ----
    for (int r = rr; r < N_DRUG; r += 32)
        hout[(size_t)r * DIM + c0 + c] = fs[r * FS + c];
}

extern "C" void kernel_launch(void* const* d_in, const int* in_sizes, int n_in,
                              void* d_out, int out_size, void* d_ws, size_t ws_size,
                              hipStream_t stream)
{
    const float* drugW = (const float*)d_in[0];
    const float* relaW = (const float*)d_in[1];
    const float* entW  = (const float*)d_in[2];
    const float* Wa    = (const float*)d_in[3];
    const float* linW  = (const float*)d_in[4];
    const float* linb  = (const float*)d_in[5];
    const float* gamma = (const float*)d_in[6];
    const float* beta  = (const float*)d_in[7];
    const int* drug_name = (const int*)d_in[8];
    const int* adj_tail  = (const int*)d_in[9];
    const int* adj_rel   = (const int*)d_in[10];
    const int* nbr_idx   = (const int*)d_in[11];
    const int* nbr_deg   = (const int*)d_in[12];
    const int* epoch     = (const int*)d_in[13];

    float* out = (float*)d_out;    // h lives in d_out; scan updates in place

    // workspace layout (16B-aligned):
    //   linP : 1024*512*4 = 2,097,152   @ 0
    //   relaP:  200*512*4 =   409,600   @ 2,097,152
    //   cat  : 572*1024*4 = 2,342,912   @ 2,506,752   (total ~4.85 MB)
    float* linP  = (float*)d_ws;
    float* relaP = (float*)((char*)d_ws + 2097152);
    float* cat   = (float*)((char*)d_ws + 2506752);

    prep_kernel<<<928, 256, 0, stream>>>(Wa, relaW, linW, linP, relaP);
    attn_kernel<<<N_DRUG, 256, 0, stream>>>(drugW, relaP, entW, drug_name,
                                            adj_tail, adj_rel, cat);
    gemm_h<<<dim3(72, 4), 512, 0, stream>>>(cat, linP, linb, out);
    scan_kernel<<<32, 512, 0, stream>>>(out, gamma, beta, nbr_idx, nbr_deg, epoch);
}

// Round 5
// 226.390 us; speedup vs baseline: 1.3057x; 1.0032x over previous
//
#include <hip/hip_runtime.h>

#define N_DRUG 572
#define DIM 512
#define MAXDEG 32
#define FS 17            // scan LDS stride: 16 cols + 1 pad

// ---------------------------------------------------------------------------
// prep_kernel: one launch, two independent jobs split by block range.
//  blocks [0,512):  pack linW (1024x512) into K-major panels
//                   linP[c>>6][k4][c&63][4k] -> gemm_h reads 1KB dwordx4/4k.
//  blocks [512,928): relaP[200][512] = relaW @ Wa^T.  score = drugE . relaP[rel]
// ---------------------------------------------------------------------------
__global__ __launch_bounds__(256) void prep_kernel(
    const float* __restrict__ Wa, const float* __restrict__ relaW,
    const float* __restrict__ linW, float* __restrict__ linP,
    float* __restrict__ relaP)
{
    const int b = blockIdx.x;
    const int t = threadIdx.x;
    if (b < 512) {                          // ---- pack linW ----
        const int g = b * 256 + t;          // [0,131072)
        const int c = g & 511, k4 = g >> 9; // k4 in [0,256)
        const float4 v = make_float4(linW[(size_t)(k4 * 4 + 0) * 512 + c],
                                     linW[(size_t)(k4 * 4 + 1) * 512 + c],
                                     linW[(size_t)(k4 * 4 + 2) * 512 + c],
                                     linW[(size_t)(k4 * 4 + 3) * 512 + c]);
        *(float4*)&linP[((size_t)(c >> 6) * 256 + k4) * 256 + (c & 63) * 4] = v;
        return;
    }
    // ---- relaP = relaW @ Wa^T ----
    const int bb = b - 512;                 // [0,416): 13 r-groups x 32 k-panels
    const int rb = bb >> 5, kb = bb & 31;
    const int wv = t >> 6, l = t & 63;
    const int r0 = rb * 16 + wv * 4;        // 4 rows per wave
    const int k0 = kb * 16;                 // 16 output cols per wave

    float a[4][8];
    #pragma unroll
    for (int rr = 0; rr < 4; ++rr) {
        const float4* ap = (const float4*)(relaW + (size_t)min(r0 + rr, 199) * 512 + l * 8);
        const float4 x = ap[0], y = ap[1];
        a[rr][0] = x.x; a[rr][1] = x.y; a[rr][2] = x.z; a[rr][3] = x.w;
        a[rr][4] = y.x; a[rr][5] = y.y; a[rr][6] = y.z; a[rr][7] = y.w;
    }
    float acc[64];
    #pragma unroll
    for (int i = 0; i < 64; ++i) acc[i] = 0.f;
    #pragma unroll
    for (int kk = 0; kk < 16; ++kk) {       // full unroll: acc index compile-time
        const float4* bp = (const float4*)(Wa + (size_t)(k0 + kk) * 512 + l * 8);
        const float4 x = bp[0], y = bp[1];
        const float bv[8] = {x.x, x.y, x.z, x.w, y.x, y.y, y.z, y.w};
        #pragma unroll
        for (int rr = 0; rr < 4; ++rr) {
            float s = acc[rr * 16 + kk];
            #pragma unroll
            for (int j = 0; j < 8; ++j) s = fmaf(a[rr][j], bv[j], s);
            acc[rr * 16 + kk] = s;
        }
    }
    #pragma unroll
    for (int off = 1; off <= 32; off <<= 1) {
        #pragma unroll
        for (int i = 0; i < 64; ++i) acc[i] += __shfl_xor(acc[i], off, 64);
    }
    float outv = acc[0];
    #pragma unroll
    for (int i = 1; i < 64; ++i) outv = (l == i) ? acc[i] : outv;
    const int rr = l >> 4, kk = l & 15;
    if (r0 + rr < 200) relaP[(size_t)(r0 + rr) * 512 + k0 + kk] = outv;
}

// ---------------------------------------------------------------------------
// attn_kernel: one block per drug. scores (vs relaP) -> softmax -> agg gather.
// Writes cat[d] = [agg | drug_e]. (unchanged)
// ---------------------------------------------------------------------------
__global__ __launch_bounds__(256) void attn_kernel(
    const float* __restrict__ drugW, const float* __restrict__ relaP,
    const float* __restrict__ entW, const int* __restrict__ dn,
    const int* __restrict__ adj_tail, const int* __restrict__ adj_rel,
    float* __restrict__ cat)
{
    __shared__ float at[64];
    __shared__ int tails[64];
    __shared__ int rels[64];
    const int d = blockIdx.x;
    const int t = threadIdx.x;
    const int w = t >> 6, lane = t & 63;

    if (t < 64) {
        tails[t] = adj_tail[d * 64 + t];
        rels[t]  = adj_rel[d * 64 + t];
    }
    const int rd = dn[d];
    float qv[8];
    {
        const float4* qp = (const float4*)(drugW + (size_t)rd * 512 + lane * 8);
        const float4 x = qp[0], y = qp[1];
        qv[0] = x.x; qv[1] = x.y; qv[2] = x.z; qv[3] = x.w;
        qv[4] = y.x; qv[5] = y.y; qv[6] = y.z; qv[7] = y.w;
    }
    __syncthreads();

    #pragma unroll 4
    for (int kk = 0; kk < 16; ++kk) {
        const int k = w * 16 + kk;
        const float4* p = (const float4*)(relaP + (size_t)rels[k] * 512 + lane * 8);
        const float4 x = p[0], y = p[1];
        float s = 0.f;
        s = fmaf(qv[0], x.x, s); s = fmaf(qv[1], x.y, s);
        s = fmaf(qv[2], x.z, s); s = fmaf(qv[3], x.w, s);
        s = fmaf(qv[4], y.x, s); s = fmaf(qv[5], y.y, s);
        s = fmaf(qv[6], y.z, s); s = fmaf(qv[7], y.w, s);
        #pragma unroll
        for (int off = 32; off >= 1; off >>= 1) s += __shfl_xor(s, off, 64);
        if (lane == 0) at[k] = s * 0.0441941738241592f;   // 1/sqrt(512)
    }
    __syncthreads();

    if (w == 0) {
        const float s = at[lane];
        float m = s;
        #pragma unroll
        for (int off = 32; off >= 1; off >>= 1) m = fmaxf(m, __shfl_xor(m, off, 64));
        const float e = __expf(s - m);
        float sum = e;
        #pragma unroll
        for (int off = 32; off >= 1; off >>= 1) sum += __shfl_xor(sum, off, 64);
        at[lane] = e / sum;
    }
    __syncthreads();

    {
        const int c2 = t * 2;
        float a0 = 0.f, a1 = 0.f;
        #pragma unroll 8
        for (int k = 0; k < 64; ++k) {
            const float ak = at[k];
            const float2 e = *(const float2*)(entW + (size_t)tails[k] * 512 + c2);
            a0 = fmaf(ak, e.x, a0);
            a1 = fmaf(ak, e.y, a1);
        }
        float* o = cat + (size_t)d * 1024;
        *(float2*)&o[c2] = make_float2(a0, a1);
        const float2 de = *(const float2*)(drugW + (size_t)rd * 512 + c2);
        *(float2*)&o[512 + c2] = de;
    }
}

// ---------------------------------------------------------------------------
// gemm_h v3: out[572][512] = ReLU(cat @ linW + b). (unchanged)
// ---------------------------------------------------------------------------
__global__ __launch_bounds__(512) void gemm_h(
    const float* __restrict__ A, const float* __restrict__ linP,
    const float* __restrict__ bias, float* __restrict__ out)
{
    __shared__ float red[8][8][128];      // 32 KB
    const int t = threadIdx.x;
    const int wv = t >> 6, lane = t & 63;
    const int r0 = blockIdx.x * 8;
    const int half = lane >> 5;           // which 64-col linP panel of the pair
    const int cw = (lane * 2) & 63;       // col within panel (even)

    const float* wp = linP + ((size_t)(blockIdx.y * 2 + half) * 256 + wv * 32) * 256
                    + cw * 4;
    const float* ap[8];
    #pragma unroll
    for (int r = 0; r < 8; ++r)
        ap[r] = A + (size_t)min(r0 + r, N_DRUG - 1) * 1024 + wv * 128;

    float acc0[8] = {0.f, 0.f, 0.f, 0.f, 0.f, 0.f, 0.f, 0.f};
    float acc1[8] = {0.f, 0.f, 0.f, 0.f, 0.f, 0.f, 0.f, 0.f};
    #pragma unroll 2
    for (int k4 = 0; k4 < 32; ++k4) {
        const float4 w0 = *(const float4*)(wp + (size_t)k4 * 256);
        const float4 w1 = *(const float4*)(wp + (size_t)k4 * 256 + 4);
        #pragma unroll
        for (int r = 0; r < 8; ++r) {
            const float4 a = *(const float4*)(ap[r] + k4 * 4);   // wave-uniform bcast
            acc0[r] = fmaf(a.x, w0.x, acc0[r]);
            acc0[r] = fmaf(a.y, w0.y, acc0[r]);
            acc0[r] = fmaf(a.z, w0.z, acc0[r]);
            acc0[r] = fmaf(a.w, w0.w, acc0[r]);
            acc1[r] = fmaf(a.x, w1.x, acc1[r]);
            acc1[r] = fmaf(a.y, w1.y, acc1[r]);
            acc1[r] = fmaf(a.z, w1.z, acc1[r]);
            acc1[r] = fmaf(a.w, w1.w, acc1[r]);
        }
    }
    #pragma unroll
    for (int r = 0; r < 8; ++r)
        *(float2*)&red[wv][r][lane * 2] = make_float2(acc0[r], acc1[r]);
    __syncthreads();

    #pragma unroll
    for (int u = 0; u < 2; ++u) {
        const int o = u * 512 + t;
        const int r = o >> 7, cc = o & 127;
        if (r0 + r < N_DRUG) {
            float v = red[0][r][cc];
            #pragma unroll
            for (int w = 1; w < 8; ++w) v += red[w][r][cc];
            v += bias[blockIdx.y * 128 + cc];
            out[(size_t)(r0 + r) * 512 + blockIdx.y * 128 + cc] = fmaxf(v, 0.f);
        }
    }
}

// ---------------------------------------------------------------------------
// Fused BN + sequential smoothing scan. 32 blocks x 16 cols, 512 threads.
// v2: WAVE-SYNCHRONOUS round loop. Wave w owns cols {2w, 2w+1}; lane =
// 16 node-slots x 2 halves x 2 cols. Group schedule computed redundantly
// per wave via __ballot on read-only mxs -> ZERO barriers / zero LDS
// round-trips in the serial loop. Within-wave LDS ops are program-ordered,
// so "all reads before the write" holds by instruction order (compiler
// fence pins it). Staging/BN/stats/writeback unchanged (barriers kept).
// ---------------------------------------------------------------------------
__global__ __launch_bounds__(512) void scan_kernel(
    float* hout, const float* __restrict__ gamma, const float* __restrict__ beta,
    const int* __restrict__ nbr_idx, const int* __restrict__ nbr_deg,
    const int* __restrict__ epoch)
{
    __shared__ float fs[(N_DRUG + 1) * FS];      // row N_DRUG = zeros (dummy)
    __shared__ alignas(16) unsigned short offs[N_DRUG * MAXDEG];  // row*FS, dummy=N_DRUG*FS
    __shared__ float2 ivw[N_DRUG];               // (0.5/deg, 0.5) or (0,1)
    __shared__ int   mxs[N_DRUG];                // max lower-dep row, -1 if none
    __shared__ float part[2][32][16];
    __shared__ float bnp[2][16];

    const int t  = threadIdx.x;
    const int c  = t & 15;
    const int rr = t >> 4;         // staging row-group 0..31
    const int c0 = blockIdx.x * 16;

    // ---- phase 0a: padded, pre-scaled u16 neighbor table; mx; ivw ----
    for (int i = t; i < N_DRUG; i += 512) {
        const int d = nbr_deg[i];
        ivw[i] = (d > 0) ? make_float2(0.5f / (float)d, 0.5f) : make_float2(0.f, 1.f);
        const int4* np = (const int4*)&nbr_idx[i * MAXDEG];
        unsigned* op = (unsigned*)&offs[i * MAXDEG];
        int mx = -1;
        #pragma unroll
        for (int u = 0; u < 8; ++u) {
            int4 qq = np[u];
            const int b = u * 4;
            qq.x = (b + 0 < d) ? qq.x : N_DRUG;
            qq.y = (b + 1 < d) ? qq.y : N_DRUG;
            qq.z = (b + 2 < d) ? qq.z : N_DRUG;
            qq.w = (b + 3 < d) ? qq.w : N_DRUG;
            mx = max(mx, (qq.x < i) ? qq.x : -1);
            mx = max(mx, (qq.y < i) ? qq.y : -1);
            mx = max(mx, (qq.z < i) ? qq.z : -1);
            mx = max(mx, (qq.w < i) ? qq.w : -1);
            op[2 * u]     = (unsigned)(qq.x * FS) | ((unsigned)(qq.y * FS) << 16);
            op[2 * u + 1] = (unsigned)(qq.z * FS) | ((unsigned)(qq.w * FS) << 16);
        }
        mxs[i] = mx;
    }

    // ---- phase 0b: stage fs (already bias+ReLU'd); partial stats ----
    {
        float sl = 0.f, ql = 0.f;
        for (int r = rr; r < N_DRUG; r += 32) {
            const float v = hout[(size_t)r * DIM + c0 + c];
            fs[r * FS + c] = v;
            sl += v;
            ql = fmaf(v, v, ql);
        }
        part[0][rr][c] = sl;
        part[1][rr][c] = ql;
    }
    if (t < FS) fs[N_DRUG * FS + t] = 0.f;
    __syncthreads();

    // ---- phase 1: stats finalize (t<16) ----
    if (t < 16) {
        float s = 0.f, sq = 0.f;
        #pragma unroll
        for (int k = 0; k < 32; ++k) { s += part[0][k][t]; sq += part[1][k][t]; }
        const float mean = s * (1.f / N_DRUG);
        const float var = sq * (1.f / N_DRUG) - mean * mean;
        const float rstd = rsqrtf(var + 1e-5f);
        const float scl = gamma[c0 + t] * rstd;
        bnp[0][t] = scl;
        bnp[1][t] = beta[c0 + t] - mean * scl;
    }
    __syncthreads();

    // ---- phase 2: BN apply ----
    {
        const float scl = bnp[0][c];
        const float shf = bnp[1][c];
        for (int r = rr; r < N_DRUG; r += 32)
            fs[r * FS + c] = fmaf(fs[r * FS + c], scl, shf);
    }
    __syncthreads();

    // ---- rounds: wave-synchronous, no barriers ----
    if (epoch[0] > 1) {
        const int wv   = t >> 6;            // wave 0..7 owns cols 2wv,2wv+1
        const int lane = t & 63;
        const int j    = lane >> 2;         // node slot 0..15
        const int hh   = (lane >> 1) & 1;   // neighbor half
        const int cl   = (wv << 1) | (lane & 1);   // local col 0..15

        int gs = 0;
        int ge;
        {
            const int jj = 1 + lane;
            const bool flag = (lane >= 15) || (jj >= N_DRUG) ||
                              (mxs[min(jj, N_DRUG - 1)] >= 0);
            ge = 1 + (int)__builtin_ctzll(__ballot(flag) & 0xFFFFULL);
        }
        uint4 ca, cb;
        {
            const uint4* p = (const uint4*)&offs[j * MAXDEG + hh * 16];
            ca = p[0]; cb = p[1];
        }
        while (gs < N_DRUG) {
            const bool pred = (gs + j) < ge;
            float s0 = 0.f, s1 = 0.f;
#define G2(W) { s0 += fs[(W & 0xffffu) + cl]; s1 += fs[(W >> 16) + cl]; }
            if (pred) { G2(ca.x) G2(ca.y) G2(ca.z) G2(ca.w)
                        G2(cb.x) G2(cb.y) G2(cb.z) G2(cb.w) }
#undef G2
            uint4 na, nb;
            {
                const uint4* p = (const uint4*)&offs[min(ge + j, N_DRUG - 1) * MAXDEG + hh * 16];
                na = p[0]; nb = p[1];
            }
            int genext;
            {
                const int jj = ge + 1 + lane;
                const bool flag = (lane >= 15) || (jj >= N_DRUG) ||
                                  (mxs[min(jj, N_DRUG - 1)] >= ge);
                genext = ge + 1 + (int)__builtin_ctzll(__ballot(flag) & 0xFFFFULL);
            }
            float nv = 0.f;
            if (pred) {
                const float cur = fs[(gs + j) * FS + cl];
                const float2 iw = ivw[gs + j];
                float sh = s0 + s1;
                sh += __shfl_xor(sh, 2, 64);     // combine the two halves
                nv = fmaf(sh, iw.x, cur * iw.y);
            }
            asm volatile("" ::: "memory");       // reads stay before the write
            if (pred && hh == 0) fs[(gs + j) * FS + cl] = nv;
            asm volatile("" ::: "memory");       // write stays before next reads
            gs = ge;
            ge = genext;
            ca = na; cb = nb;
        }
    }
    __syncthreads();   // cols remap across waves for writeback

    // ---- write back ----
    for (int r = rr; r < N_DRUG; r += 32)
        hout[(size_t)r * DIM + c0 + c] = fs[r * FS + c];
}

extern "C" void kernel_launch(void* const* d_in, const int* in_sizes, int n_in,
                              void* d_out, int out_size, void* d_ws, size_t ws_size,
                              hipStream_t stream)
{
    const float* drugW = (const float*)d_in[0];
    const float* relaW = (const float*)d_in[1];
    const float* entW  = (const float*)d_in[2];
    const float* Wa    = (const float*)d_in[3];
    const float* linW  = (const float*)d_in[4];
    const float* linb  = (const float*)d_in[5];
    const float* gamma = (const float*)d_in[6];
    const float* beta  = (const float*)d_in[7];
    const int* drug_name = (const int*)d_in[8];
    const int* adj_tail  = (const int*)d_in[9];
    const int* adj_rel   = (const int*)d_in[10];
    const int* nbr_idx   = (const int*)d_in[11];
    const int* nbr_deg   = (const int*)d_in[12];
    const int* epoch     = (const int*)d_in[13];

    float* out = (float*)d_out;    // h lives in d_out; scan updates in place

    // workspace layout (16B-aligned):
    //   linP : 1024*512*4 = 2,097,152   @ 0
    //   relaP:  200*512*4 =   409,600   @ 2,097,152
    //   cat  : 572*1024*4 = 2,342,912   @ 2,506,752   (total ~4.85 MB)
    float* linP  = (float*)d_ws;
    float* relaP = (float*)((char*)d_ws + 2097152);
    float* cat   = (float*)((char*)d_ws + 2506752);

    prep_kernel<<<928, 256, 0, stream>>>(Wa, relaW, linW, linP, relaP);
    attn_kernel<<<N_DRUG, 256, 0, stream>>>(drugW, relaP, entW, drug_name,
                                            adj_tail, adj_rel, cat);
    gemm_h<<<dim3(72, 4), 512, 0, stream>>>(cat, linP, linb, out);
    scan_kernel<<<32, 512, 0, stream>>>(out, gamma, beta, nbr_idx, nbr_deg, epoch);
}